// Round 1
// baseline (327.978 us; speedup 1.0000x reference)
//
#include <hip/hip_runtime.h>
#include <hip/hip_bf16.h>

// GlobalPoolDistance: RBF-kernel MMD over 3x3 patch unfolds.
// x,y: (8,3,64,64) f32. N = 62*62 = 3844 patches, d = 27.
// loss = mean_b( -2*K(x,y) + K(x,x) + K(y,y) ),  K = mean_{i,j} exp(-||xi-yj||^2/SIG2)
// SIG2 = (0.06*9)^2 = 0.2916.
//
// Strategy: gram expansion d2 = sqx + sqy - 2<x,y>; exp via exp2:
//   exp(-d2/SIG2) = exp2( p[i] + p[j] + g*2L ),  p = -sq*L,  L = log2(e)/SIG2.
// Workspace: U[16][28][3968] f32 (rows 0..26 = patch dims, row 27 = p; cols
// 3844..3967 padded with dims=0, p=-1e30 so padded pairs contribute 0).
// ws bytes needed: 16*28*3968*4 + 128 = 7,110,784.

#define NP     3844
#define NPAD   3968
#define NTILE  31      // 31 * 128 = 3968
#define DDIM   27
#define DPAD   28

static constexpr float L_F   = 4.9475824173972215f;   // log2(e)/0.2916
static constexpr float C2L_F = 9.895164834794443f;    // 2*L

__global__ __launch_bounds__(256) void gp_unfold(const float* __restrict__ x,
                                                 const float* __restrict__ y,
                                                 float* __restrict__ U) {
    int i = blockIdx.x * 256 + threadIdx.x;      // 16*27*3968 threads
    if (i >= 16 * DDIM * NPAD) return;
    int n = i % NPAD;
    int rest = i / NPAD;
    int d = rest % DDIM;
    int im = rest / DDIM;                        // im = img*8 + b
    int b = im & 7, img = im >> 3;
    float v = 0.0f;
    if (n < NP) {
        int r = n / 62, c = n % 62;
        int ch = d / 9, k = d % 9, pr = k / 3, pc = k % 3;
        const float* src = img ? y : x;
        v = src[(((b * 3 + ch) * 64) + r + pr) * 64 + (c + pc)];
    }
    U[((size_t)im * DPAD + d) * NPAD + n] = v;
}

__global__ __launch_bounds__(256) void gp_norms(float* __restrict__ U) {
    int i = blockIdx.x * 256 + threadIdx.x;      // 16*3968 threads
    if (i >= 16 * NPAD) return;
    int n = i % NPAD, im = i / NPAD;
    float* base = U + (size_t)im * DPAD * NPAD;
    float p = -1e30f;
    if (n < NP) {
        float sq = 0.0f;
#pragma unroll
        for (int d = 0; d < DDIM; ++d) {
            float v = base[d * NPAD + n];
            sq = fmaf(v, v, sq);
        }
        p = -L_F * sq;
    }
    base[DDIM * NPAD + n] = p;
}

__global__ void gp_zero(float* __restrict__ acc) {
    if (threadIdx.x < 32) acc[threadIdx.x] = 0.0f;
}

__global__ __launch_bounds__(256) void gp_pairs(const float* __restrict__ U,
                                                float* __restrict__ acc) {
    const int bx = blockIdx.x, by = blockIdx.y, z = blockIdx.z;
    const int type = z >> 3, b = z & 7;
    int imA, imB;
    if (type == 0)      { imA = b;     imB = 8 + b; }   // xy
    else if (type == 1) { imA = b;     imB = b;     }   // xx
    else                { imA = 8 + b; imB = 8 + b; }   // yy

    const float* A = U + (size_t)imA * DPAD * NPAD + bx * 128;
    const float* B = U + (size_t)imB * DPAD * NPAD + by * 128;

    __shared__ float As[DPAD][128];
    __shared__ float Bs[DPAD][128];
    __shared__ float red[256];

    const int t = threadIdx.x;
    // stage 28 rows x 128 cols per side, as float4 (896 float4 per side)
    for (int k = t; k < DPAD * 32; k += 256) {
        int d = k >> 5, c4 = k & 31;
        ((float4*)As[d])[c4] = *(const float4*)(A + d * NPAD + c4 * 4);
        ((float4*)Bs[d])[c4] = *(const float4*)(B + d * NPAD + c4 * 4);
    }
    __syncthreads();

    const int i0 = (t & 15) * 8;
    const int j0 = (t >> 4) * 8;

    float g[8][8];
#pragma unroll
    for (int i = 0; i < 8; ++i)
#pragma unroll
        for (int j = 0; j < 8; ++j) g[i][j] = 0.0f;

    for (int d = 0; d < DDIM; ++d) {
        float4 a0 = *(const float4*)&As[d][i0];
        float4 a1 = *(const float4*)&As[d][i0 + 4];
        float4 b0 = *(const float4*)&Bs[d][j0];
        float4 b1 = *(const float4*)&Bs[d][j0 + 4];
        float av[8] = {a0.x, a0.y, a0.z, a0.w, a1.x, a1.y, a1.z, a1.w};
        float bv[8] = {b0.x, b0.y, b0.z, b0.w, b1.x, b1.y, b1.z, b1.w};
#pragma unroll
        for (int i = 0; i < 8; ++i)
#pragma unroll
            for (int j = 0; j < 8; ++j) g[i][j] = fmaf(av[i], bv[j], g[i][j]);
    }

    // epilogue: p values live in row 27
    float4 pa0 = *(const float4*)&As[DDIM][i0];
    float4 pa1 = *(const float4*)&As[DDIM][i0 + 4];
    float4 pb0 = *(const float4*)&Bs[DDIM][j0];
    float4 pb1 = *(const float4*)&Bs[DDIM][j0 + 4];
    float pav[8] = {pa0.x, pa0.y, pa0.z, pa0.w, pa1.x, pa1.y, pa1.z, pa1.w};
    float pbv[8] = {pb0.x, pb0.y, pb0.z, pb0.w, pb1.x, pb1.y, pb1.z, pb1.w};

    float s = 0.0f;
#pragma unroll
    for (int i = 0; i < 8; ++i)
#pragma unroll
        for (int j = 0; j < 8; ++j) {
            float targ = fmaf(g[i][j], C2L_F, pav[i] + pbv[j]);
            s += __builtin_amdgcn_exp2f(targ);
        }

    // block reduce
    red[t] = s;
    __syncthreads();
#pragma unroll
    for (int off = 128; off > 0; off >>= 1) {
        if (t < off) red[t] += red[t + off];
        __syncthreads();
    }
    if (t == 0) atomicAdd(&acc[z], red[0]);
}

__global__ void gp_final(const float* __restrict__ acc, float* __restrict__ out) {
    if (threadIdx.x == 0) {
        double s = 0.0;
        for (int b = 0; b < 8; ++b)
            s += -2.0 * (double)acc[b] + (double)acc[8 + b] + (double)acc[16 + b];
        out[0] = (float)(s / (8.0 * (double)NP * (double)NP));
    }
}

extern "C" void kernel_launch(void* const* d_in, const int* in_sizes, int n_in,
                              void* d_out, int out_size, void* d_ws, size_t ws_size,
                              hipStream_t stream) {
    const float* x = (const float*)d_in[0];
    const float* y = (const float*)d_in[1];
    float* U = (float*)d_ws;
    float* acc = U + (size_t)16 * DPAD * NPAD;   // 24 floats used (32 zeroed)

    gp_zero<<<1, 32, 0, stream>>>(acc);
    gp_unfold<<<(16 * DDIM * NPAD + 255) / 256, 256, 0, stream>>>(x, y, U);
    gp_norms<<<(16 * NPAD + 255) / 256, 256, 0, stream>>>(U);
    gp_pairs<<<dim3(NTILE, NTILE, 24), 256, 0, stream>>>(U, acc);
    gp_final<<<1, 1, 0, stream>>>(acc, (float*)d_out);
}

// Round 2
// 196.660 us; speedup vs baseline: 1.6677x; 1.6677x over previous
//
#include <hip/hip_runtime.h>
#include <hip/hip_bf16.h>

// GlobalPoolDistance: RBF-kernel MMD over 3x3 patch unfolds (8,3,64,64) f32.
// N = 62*62 = 3844 patches, d = 27 (padded to K=32). SIG2 = 0.2916.
// exp(-d2/SIG2) = exp2( p_i + p_j + g*2L ), p = -L*||patch||^2, L = log2e/SIG2.
//
// R2: gram via split-bf16 MFMA (g = hi*hi + hi*lo + lo*hi), fragments loaded
// directly from global (L2-resident, coalesced, zero LDS staging), xx/yy
// tile-level symmetry (upper triangle, off-diagonal tiles weighted 2x).
//
// ws layout: Uh[16][3968][32] bf16 | Ul[...] bf16 | P[16][3968] f32 | acc[32]
// total = 8,380,544 bytes.

#define NP    3844
#define NPAD  3968
#define NT    31        // 128-wide tiles per dim
#define KP    32
#define NTRI  496       // NT*(NT+1)/2

static constexpr float L_F   = 4.9475824173972215f;   // log2(e)/0.2916
static constexpr float C2L_F = 9.895164834794443f;    // 2*L

using bf16x8 = __attribute__((ext_vector_type(8))) short;
using f32x4  = __attribute__((ext_vector_type(4))) float;

__device__ inline unsigned short f2bf(float f) {
    union { float f; unsigned u; } v; v.f = f;
    unsigned r = v.u + 0x7FFFu + ((v.u >> 16) & 1u);   // RNE (no NaN inputs)
    return (unsigned short)(r >> 16);
}
__device__ inline float bf2f(unsigned short h) {
    union { unsigned u; float f; } v; v.u = ((unsigned)h) << 16;
    return v.f;
}

// One thread per (im, patch): emit bf16 hi/lo split (K padded to 32) + P.
__global__ __launch_bounds__(256) void gp_prep(const float* __restrict__ x,
                                               const float* __restrict__ y,
                                               unsigned short* __restrict__ Uh,
                                               unsigned short* __restrict__ Ul,
                                               float* __restrict__ P) {
    int i = blockIdx.x * 256 + threadIdx.x;          // 16*NPAD = 63488
    if (i >= 16 * NPAD) return;
    int n = i % NPAD, im = i / NPAD;
    int b = im & 7;
    const float* src = (im >> 3) ? y : x;

    unsigned short h[32], lo[32];
    if (n < NP) {
        int r = n / 62, c = n % 62;
        float sq = 0.0f;
#pragma unroll
        for (int ch = 0; ch < 3; ++ch)
#pragma unroll
            for (int pr = 0; pr < 3; ++pr)
#pragma unroll
                for (int pc = 0; pc < 3; ++pc) {
                    int k = ch * 9 + pr * 3 + pc;
                    float v = src[(((b * 3 + ch) * 64) + r + pr) * 64 + (c + pc)];
                    unsigned short hb = f2bf(v);
                    h[k] = hb;
                    lo[k] = f2bf(v - bf2f(hb));
                    sq = fmaf(v, v, sq);
                }
#pragma unroll
        for (int k = 27; k < 32; ++k) { h[k] = 0; lo[k] = 0; }
        P[i] = -L_F * sq;
    } else {
#pragma unroll
        for (int k = 0; k < 32; ++k) { h[k] = 0; lo[k] = 0; }
        P[i] = -1e30f;
    }

    unsigned wh[16], wl[16];
#pragma unroll
    for (int q = 0; q < 16; ++q) {
        wh[q] = (unsigned)h[2 * q] | ((unsigned)h[2 * q + 1] << 16);
        wl[q] = (unsigned)lo[2 * q] | ((unsigned)lo[2 * q + 1] << 16);
    }
    uint4* dh = (uint4*)(Uh + (size_t)i * KP);
    uint4* dl = (uint4*)(Ul + (size_t)i * KP);
#pragma unroll
    for (int q = 0; q < 4; ++q) {
        dh[q] = make_uint4(wh[4 * q], wh[4 * q + 1], wh[4 * q + 2], wh[4 * q + 3]);
        dl[q] = make_uint4(wl[4 * q], wl[4 * q + 1], wl[4 * q + 2], wl[4 * q + 3]);
    }
}

__global__ void gp_zero(float* __restrict__ acc) {
    if (threadIdx.x < 32) acc[threadIdx.x] = 0.0f;
}

// 128x128 pair tile per block (4 waves x 32-row strip). Fragments straight
// from global. blockIdx.x enumerates: [0, 8*NT*NT) = xy full grid;
// then xx, yy upper-triangle tiles (off-diagonal weighted 2x).
__global__ __launch_bounds__(256) void gp_pairs2(const unsigned short* __restrict__ Uh,
                                                 const unsigned short* __restrict__ Ul,
                                                 const float* __restrict__ P,
                                                 float* __restrict__ acc) {
    int id = blockIdx.x;
    int type, b, bx, by;
    float weight = 1.0f;
    if (id < 8 * NT * NT) {
        type = 0; b = id / (NT * NT);
        int t2 = id % (NT * NT); bx = t2 / NT; by = t2 % NT;
    } else {
        int id2 = id - 8 * NT * NT;
        type = 1 + id2 / (8 * NTRI);
        int r = id2 % (8 * NTRI);
        b = r / NTRI;
        int t2 = r % NTRI;
        bx = (int)((63.0f - sqrtf(3969.0f - 8.0f * (float)t2)) * 0.5f);
        while (bx * (63 - bx) / 2 > t2) --bx;
        while ((bx + 1) * (62 - bx) / 2 <= t2) ++bx;
        by = bx + (t2 - bx * (63 - bx) / 2);
        weight = (bx == by) ? 1.0f : 2.0f;
    }
    int imA, imB;
    if (type == 0)      { imA = b;     imB = 8 + b; }
    else if (type == 1) { imA = b;     imB = b;     }
    else                { imA = 8 + b; imB = 8 + b; }

    const int t = threadIdx.x;
    const int w = t >> 6;
    const int l = t & 63;
    const int l15 = l & 15, lhi = l >> 4;

    const int rowBase = bx * 128 + w * 32;
    const int colBase = by * 128;

    bf16x8 ah[2], al[2];
    f32x4 pav[2];
#pragma unroll
    for (int rg = 0; rg < 2; ++rg) {
        size_t e = ((size_t)(imA * NPAD + rowBase + rg * 16 + l15)) * KP + lhi * 8;
        ah[rg] = *(const bf16x8*)(Uh + e);
        al[rg] = *(const bf16x8*)(Ul + e);
        pav[rg] = *(const f32x4*)(P + imA * NPAD + rowBase + rg * 16 + lhi * 4);
    }
    bf16x8 bh[8], bl[8];
    float pbv[8];
#pragma unroll
    for (int cg = 0; cg < 8; ++cg) {
        size_t e = ((size_t)(imB * NPAD + colBase + cg * 16 + l15)) * KP + lhi * 8;
        bh[cg] = *(const bf16x8*)(Uh + e);
        bl[cg] = *(const bf16x8*)(Ul + e);
        pbv[cg] = P[imB * NPAD + colBase + cg * 16 + l15];
    }

    float s = 0.0f;
#pragma unroll
    for (int rg = 0; rg < 2; ++rg)
#pragma unroll
        for (int cg = 0; cg < 8; ++cg) {
            f32x4 g = {0.0f, 0.0f, 0.0f, 0.0f};
            g = __builtin_amdgcn_mfma_f32_16x16x32_bf16(al[rg], bh[cg], g, 0, 0, 0);
            g = __builtin_amdgcn_mfma_f32_16x16x32_bf16(ah[rg], bl[cg], g, 0, 0, 0);
            g = __builtin_amdgcn_mfma_f32_16x16x32_bf16(ah[rg], bh[cg], g, 0, 0, 0);
#pragma unroll
            for (int j = 0; j < 4; ++j) {
                float targ = fmaf(g[j], C2L_F, pav[rg][j] + pbv[cg]);
                s += __builtin_amdgcn_exp2f(targ);
            }
        }

    // wave shuffle reduce, then 4 partials via LDS
#pragma unroll
    for (int o = 32; o > 0; o >>= 1) s += __shfl_down(s, o, 64);
    __shared__ float red[4];
    if (l == 0) red[w] = s;
    __syncthreads();
    if (t == 0)
        atomicAdd(&acc[type * 8 + b], (red[0] + red[1] + red[2] + red[3]) * weight);
}

__global__ void gp_final(const float* __restrict__ acc, float* __restrict__ out) {
    if (threadIdx.x == 0) {
        double s = 0.0;
        for (int b = 0; b < 8; ++b)
            s += -2.0 * (double)acc[b] + (double)acc[8 + b] + (double)acc[16 + b];
        out[0] = (float)(s / (8.0 * (double)NP * (double)NP));
    }
}

extern "C" void kernel_launch(void* const* d_in, const int* in_sizes, int n_in,
                              void* d_out, int out_size, void* d_ws, size_t ws_size,
                              hipStream_t stream) {
    const float* x = (const float*)d_in[0];
    const float* y = (const float*)d_in[1];
    unsigned short* Uh = (unsigned short*)d_ws;
    unsigned short* Ul = Uh + (size_t)16 * NPAD * KP;
    float* P = (float*)(Ul + (size_t)16 * NPAD * KP);
    float* acc = P + (size_t)16 * NPAD;

    gp_zero<<<1, 32, 0, stream>>>(acc);
    gp_prep<<<(16 * NPAD) / 256, 256, 0, stream>>>(x, y, Uh, Ul, P);
    const int nblk = 8 * NT * NT + 16 * NTRI;   // 7688 + 7936 = 15624
    gp_pairs2<<<nblk, 256, 0, stream>>>(Uh, Ul, P, acc);
    gp_final<<<1, 1, 0, stream>>>(acc, (float*)d_out);
}

// Round 3
// 86.238 us; speedup vs baseline: 3.8032x; 2.2804x over previous
//
#include <hip/hip_runtime.h>
#include <hip/hip_bf16.h>

// GlobalPoolDistance: RBF-kernel MMD over 3x3 patch unfolds (8,3,64,64) f32.
// N = 62*62 = 3844 patches, d = 27 (padded K=32). SIG2 = 0.2916.
// exp(-d2/SIG2) = exp2( p_i + p_j + g*2L ), p = -L*||patch||^2, L = log2e/SIG2.
//
// R3: column-loop blocks with double-buffered LDS B-staging (global_load_lds
// x16, transposed [slot][col] layout -> conflict-free ds_read_b128), A frags
// in registers per 128-row strip, 2x2 wave partition (64x64/wave), xx/yy
// triangle symmetry with paired-strip load balancing (992 uniform blocks).
//
// ws: Uh[16][3968][32] bf16 | Ul[...] | P[16][3968] f32 | acc[32] f32.

#define NP    3844
#define NPAD  3968
#define KP    32

static constexpr float L_F   = 4.9475824173972215f;   // log2(e)/0.2916
static constexpr float C2L_F = 9.895164834794443f;    // 2*L

using bf16x8 = __attribute__((ext_vector_type(8))) short;
using f32x4  = __attribute__((ext_vector_type(4))) float;

__device__ inline unsigned short f2bf(float f) {
    union { float f; unsigned u; } v; v.f = f;
    unsigned r = v.u + 0x7FFFu + ((v.u >> 16) & 1u);   // RNE (no NaN inputs)
    return (unsigned short)(r >> 16);
}
__device__ inline float bf2f(unsigned short h) {
    union { unsigned u; float f; } v; v.u = ((unsigned)h) << 16;
    return v.f;
}

// One thread per (im, patch): bf16 hi/lo split (K padded to 32) + P.
// Block 0 also zeroes the accumulators.
__global__ __launch_bounds__(256) void gp_prep(const float* __restrict__ x,
                                               const float* __restrict__ y,
                                               unsigned short* __restrict__ Uh,
                                               unsigned short* __restrict__ Ul,
                                               float* __restrict__ P,
                                               float* __restrict__ acc) {
    if (blockIdx.x == 0 && threadIdx.x < 32) acc[threadIdx.x] = 0.0f;
    int i = blockIdx.x * 256 + threadIdx.x;          // 16*NPAD = 63488
    if (i >= 16 * NPAD) return;
    int n = i % NPAD, im = i / NPAD;
    int b = im & 7;
    const float* src = (im >> 3) ? y : x;

    unsigned short h[32], lo[32];
    if (n < NP) {
        int r = n / 62, c = n % 62;
        float sq = 0.0f;
#pragma unroll
        for (int ch = 0; ch < 3; ++ch)
#pragma unroll
            for (int pr = 0; pr < 3; ++pr)
#pragma unroll
                for (int pc = 0; pc < 3; ++pc) {
                    int k = ch * 9 + pr * 3 + pc;
                    float v = src[(((b * 3 + ch) * 64) + r + pr) * 64 + (c + pc)];
                    unsigned short hb = f2bf(v);
                    h[k] = hb;
                    lo[k] = f2bf(v - bf2f(hb));
                    sq = fmaf(v, v, sq);
                }
#pragma unroll
        for (int k = 27; k < 32; ++k) { h[k] = 0; lo[k] = 0; }
        P[i] = -L_F * sq;
    } else {
#pragma unroll
        for (int k = 0; k < 32; ++k) { h[k] = 0; lo[k] = 0; }
        P[i] = -1e30f;
    }

    unsigned wh[16], wl[16];
#pragma unroll
    for (int q = 0; q < 16; ++q) {
        wh[q] = (unsigned)h[2 * q] | ((unsigned)h[2 * q + 1] << 16);
        wl[q] = (unsigned)lo[2 * q] | ((unsigned)lo[2 * q + 1] << 16);
    }
    uint4* dh = (uint4*)(Uh + (size_t)i * KP);
    uint4* dl = (uint4*)(Ul + (size_t)i * KP);
#pragma unroll
    for (int q = 0; q < 4; ++q) {
        dh[q] = make_uint4(wh[4 * q], wh[4 * q + 1], wh[4 * q + 2], wh[4 * q + 3]);
        dl[q] = make_uint4(wl[4 * q], wl[4 * q + 1], wl[4 * q + 2], wl[4 * q + 3]);
    }
}

// Stage one 128-col B tile (hi+lo) into a 16KB LDS buffer, transposed to
// [side 8192][slot 2048][col*16] so frag ds_read_b128 is conflict-free.
// Linear LDS dest, permuted per-lane global source (guide rule 21).
__device__ inline void stage_tile(const unsigned short* __restrict__ Uh,
                                  const unsigned short* __restrict__ Ul,
                                  int imB, int colBase, char* buf, int w, int l) {
#pragma unroll
    for (int j = 0; j < 4; ++j) {
        int q = w * 4 + j;                 // 16 chunks of 1KB
        int side = q >> 3, slot = (q >> 1) & 3, ch = q & 1;
        const unsigned short* src = (side ? Ul : Uh)
            + ((size_t)(imB * NPAD + colBase + ch * 64 + l)) * KP + slot * 8;
        char* dst = buf + side * 8192 + slot * 2048 + ch * 1024;
        __builtin_amdgcn_global_load_lds(
            (const __attribute__((address_space(1))) void*)src,
            (__attribute__((address_space(3))) void*)dst, 16, 0, 0);
    }
}

__device__ inline void item_of(int sym, int xyStrip, int pb, int len1, int idx,
                               int& strip, int& col, float& wt) {
    if (!sym)            { strip = xyStrip;  col = idx;                     wt = 1.0f; }
    else if (idx < len1) { strip = pb;       col = pb + idx;                wt = (idx == 0) ? 1.0f : 2.0f; }
    else                 { strip = 30 - pb;  col = strip + (idx - len1);    wt = (idx == len1) ? 1.0f : 2.0f; }
}

// 992 blocks: 496 xy (b,strip,half) + 2*248 sym (b, paired strips, half).
// Each block: <=16 column tiles, double-buffered LDS staging.
__global__ __launch_bounds__(256) void gp_pairs3(const unsigned short* __restrict__ Uh,
                                                 const unsigned short* __restrict__ Ul,
                                                 const float* __restrict__ P,
                                                 float* __restrict__ acc) {
    __shared__ __align__(16) char lds[2][16384];
    __shared__ float red[4];

    const int gid = blockIdx.x;
    int type, b, imA, imB, sym, xyStrip = 0, pb = 0, len1 = 0, i0, i1;
    if (gid < 496) {
        sym = 0; type = 0;
        b = gid / 62; int r = gid % 62;
        xyStrip = r >> 1; int half = r & 1;
        i0 = half * 16; i1 = half ? 31 : 16;
        imA = b; imB = 8 + b;
    } else {
        sym = 1;
        int q = gid - 496; type = 1 + q / 248; int r = q % 248;
        b = r / 31; int u = r % 31;
        int half;
        if (u == 30) { pb = 15; half = 0; } else { pb = u >> 1; half = u & 1; }
        len1 = 31 - pb;
        int total = (pb == 15) ? 16 : 32;
        i0 = half * 16; i1 = i0 + 16 < total ? i0 + 16 : total;
        imA = (type == 1) ? b : 8 + b;
        imB = imA;
    }

    const int t = threadIdx.x;
    const int w = t >> 6, l = t & 63, l15 = l & 15, lhi = l >> 4;
    const int colw = (w & 1) * 64;

    bf16x8 ah[4], al[4];
    f32x4 pav[4];
    int curStrip = -1;
    float sacc = 0.0f;

    int strip, col; float wt;
    item_of(sym, xyStrip, pb, len1, i0, strip, col, wt);
    stage_tile(Uh, Ul, imB, col * 128, &lds[0][0], w, l);
    __syncthreads();

    for (int idx = i0; idx < i1; ++idx) {
        const int cur = (idx - i0) & 1;
        item_of(sym, xyStrip, pb, len1, idx, strip, col, wt);
        if (idx + 1 < i1) {
            int s2, c2; float w2;
            item_of(sym, xyStrip, pb, len1, idx + 1, s2, c2, w2);
            stage_tile(Uh, Ul, imB, c2 * 128, &lds[cur ^ 1][0], w, l);
        }
        if (strip != curStrip) {
            curStrip = strip;
            int rowBase = strip * 128 + (w >> 1) * 64;
#pragma unroll
            for (int rg = 0; rg < 4; ++rg) {
                size_t e = ((size_t)(imA * NPAD + rowBase + rg * 16 + l15)) * KP + lhi * 8;
                ah[rg] = *(const bf16x8*)(Uh + e);
                al[rg] = *(const bf16x8*)(Ul + e);
                pav[rg] = *(const f32x4*)(P + imA * NPAD + rowBase + rg * 16 + lhi * 4);
            }
        }
        float pbv[4];
#pragma unroll
        for (int cg = 0; cg < 4; ++cg)
            pbv[cg] = P[imB * NPAD + col * 128 + colw + cg * 16 + l15];

        const char* bb = &lds[cur][0];
        bf16x8 bh[4], bl[4];
#pragma unroll
        for (int cg = 0; cg < 4; ++cg) {
            int off = lhi * 2048 + (colw + cg * 16 + l15) * 16;
            bh[cg] = *(const bf16x8*)(bb + off);
            bl[cg] = *(const bf16x8*)(bb + 8192 + off);
        }

        float ls0 = 0.f, ls1 = 0.f, ls2 = 0.f, ls3 = 0.f;
#pragma unroll
        for (int rg = 0; rg < 4; ++rg)
#pragma unroll
            for (int cg = 0; cg < 4; ++cg) {
                f32x4 g = {0.f, 0.f, 0.f, 0.f};
                g = __builtin_amdgcn_mfma_f32_16x16x32_bf16(al[rg], bh[cg], g, 0, 0, 0);
                g = __builtin_amdgcn_mfma_f32_16x16x32_bf16(ah[rg], bl[cg], g, 0, 0, 0);
                g = __builtin_amdgcn_mfma_f32_16x16x32_bf16(ah[rg], bh[cg], g, 0, 0, 0);
                ls0 += __builtin_amdgcn_exp2f(fmaf(g[0], C2L_F, pav[rg][0] + pbv[cg]));
                ls1 += __builtin_amdgcn_exp2f(fmaf(g[1], C2L_F, pav[rg][1] + pbv[cg]));
                ls2 += __builtin_amdgcn_exp2f(fmaf(g[2], C2L_F, pav[rg][2] + pbv[cg]));
                ls3 += __builtin_amdgcn_exp2f(fmaf(g[3], C2L_F, pav[rg][3] + pbv[cg]));
            }
        sacc = fmaf(wt, (ls0 + ls1) + (ls2 + ls3), sacc);
        __syncthreads();   // drains vmcnt (staging) + lgkm, then barrier
    }

#pragma unroll
    for (int o = 32; o > 0; o >>= 1) sacc += __shfl_down(sacc, o, 64);
    if (l == 0) red[w] = sacc;
    __syncthreads();
    if (t == 0) atomicAdd(&acc[type * 8 + b], (red[0] + red[1]) + (red[2] + red[3]));
}

__global__ void gp_final(const float* __restrict__ acc, float* __restrict__ out) {
    if (threadIdx.x == 0) {
        double s = 0.0;
        for (int b = 0; b < 8; ++b)
            s += -2.0 * (double)acc[b] + (double)acc[8 + b] + (double)acc[16 + b];
        out[0] = (float)(s / (8.0 * (double)NP * (double)NP));
    }
}

extern "C" void kernel_launch(void* const* d_in, const int* in_sizes, int n_in,
                              void* d_out, int out_size, void* d_ws, size_t ws_size,
                              hipStream_t stream) {
    const float* x = (const float*)d_in[0];
    const float* y = (const float*)d_in[1];
    unsigned short* Uh = (unsigned short*)d_ws;
    unsigned short* Ul = Uh + (size_t)16 * NPAD * KP;
    float* P = (float*)(Ul + (size_t)16 * NPAD * KP);
    float* acc = P + (size_t)16 * NPAD;

    gp_prep<<<(16 * NPAD) / 256, 256, 0, stream>>>(x, y, Uh, Ul, P, acc);
    gp_pairs3<<<992, 256, 0, stream>>>(Uh, Ul, P, acc);
    gp_final<<<1, 1, 0, stream>>>(acc, (float*)d_out);
}

// Round 4
// 73.754 us; speedup vs baseline: 4.4469x; 1.1693x over previous
//
#include <hip/hip_runtime.h>
#include <hip/hip_bf16.h>

// GlobalPoolDistance: RBF-kernel MMD over 3x3 patch unfolds (8,3,64,64) f32.
// N = 62*62 = 3844 patches, d = 27 (padded K=32). SIG2 = 0.2916.
// R4: p-terms baked into MFMA pad columns (A pre-scaled by 2L, col27 = 2L,
// col28 = -L*||a||^2; B col27 = -||b||^2/2, col28 = 1) so the MFMA result IS
// the exp2 argument: epilogue = exp2 + add only. Counted-vmcnt two-barrier
// K-loop (prefetch survives the barrier), 1984 balanced blocks, 32KB LDS
// (5 blocks/CU). Split-bf16 3-MFMA gram for f32-grade precision.
//
// ws: Ah|Al|Bh|Bl [16][3968][32] bf16 (4 x 4,063,232 B) + acc[32] f32.

#define NP    3844
#define NPAD  3968
#define KP    32

static constexpr float L_F   = 4.9475824173972215f;   // log2(e)/0.2916
static constexpr float C2L_F = 9.895164834794443f;    // 2*L

using bf16x8 = __attribute__((ext_vector_type(8))) short;
using f32x4  = __attribute__((ext_vector_type(4))) float;

__device__ inline unsigned short f2bf(float f) {
    union { float f; unsigned u; } v; v.f = f;
    unsigned r = v.u + 0x7FFFu + ((v.u >> 16) & 1u);   // RNE (no NaN inputs)
    return (unsigned short)(r >> 16);
}
__device__ inline float bf2f(unsigned short h) {
    union { unsigned u; float f; } v; v.u = ((unsigned)h) << 16;
    return v.f;
}
__device__ inline void pack_store(unsigned short* dst, const unsigned short* v) {
    uint4* d = (uint4*)dst;
#pragma unroll
    for (int q = 0; q < 4; ++q) {
        unsigned w0 = (unsigned)v[8 * q + 0] | ((unsigned)v[8 * q + 1] << 16);
        unsigned w1 = (unsigned)v[8 * q + 2] | ((unsigned)v[8 * q + 3] << 16);
        unsigned w2 = (unsigned)v[8 * q + 4] | ((unsigned)v[8 * q + 5] << 16);
        unsigned w3 = (unsigned)v[8 * q + 6] | ((unsigned)v[8 * q + 7] << 16);
        d[q] = make_uint4(w0, w1, w2, w3);
    }
}

// One thread per (im, patch). A-side scaled by 2L with p-cols; B-side plain.
__global__ __launch_bounds__(256) void gp_prep(const float* __restrict__ x,
                                               const float* __restrict__ y,
                                               unsigned short* __restrict__ Ah,
                                               unsigned short* __restrict__ Al,
                                               unsigned short* __restrict__ Bh,
                                               unsigned short* __restrict__ Bl,
                                               float* __restrict__ acc) {
    if (blockIdx.x == 0 && threadIdx.x < 32) acc[threadIdx.x] = 0.0f;
    int i = blockIdx.x * 256 + threadIdx.x;          // 16*NPAD = 63488
    if (i >= 16 * NPAD) return;
    int n = i % NPAD, im = i / NPAD;
    int b = im & 7;
    const float* src = (im >> 3) ? y : x;

    unsigned short hA[32], lA[32], hB[32], lB[32];
#pragma unroll
    for (int k = 0; k < 32; ++k) { hA[k] = 0; lA[k] = 0; hB[k] = 0; lB[k] = 0; }

    float sq = 0.0f;
    const bool valid = (n < NP);
    if (valid) {
        int r = n / 62, c = n % 62;
#pragma unroll
        for (int ch = 0; ch < 3; ++ch)
#pragma unroll
            for (int pr = 0; pr < 3; ++pr)
#pragma unroll
                for (int pc = 0; pc < 3; ++pc) {
                    int k = ch * 9 + pr * 3 + pc;
                    float v = src[(((b * 3 + ch) * 64) + r + pr) * 64 + (c + pc)];
                    unsigned short hb = f2bf(v);
                    hB[k] = hb; lB[k] = f2bf(v - bf2f(hb));
                    float sv = C2L_F * v;
                    unsigned short ha = f2bf(sv);
                    hA[k] = ha; lA[k] = f2bf(sv - bf2f(ha));
                    sq = fmaf(v, v, sq);
                }
    }
    // col 27: A = 2L (const), B = -sq/2 (pad: -1e30 -> exp2 -> 0)
    {
        unsigned short h = f2bf(C2L_F);
        hA[27] = h; lA[27] = f2bf(C2L_F - bf2f(h));
        float tb = valid ? -0.5f * sq : -1e30f;
        unsigned short hb = f2bf(tb);
        hB[27] = hb; lB[27] = f2bf(tb - bf2f(hb));
    }
    // col 28: A = -L*sq (pad: -1e30), B = 1
    {
        float pa = valid ? -L_F * sq : -1e30f;
        unsigned short ha = f2bf(pa);
        hA[28] = ha; lA[28] = f2bf(pa - bf2f(ha));
        hB[28] = f2bf(1.0f); lB[28] = 0;
    }

    pack_store(Ah + (size_t)i * KP, hA);
    pack_store(Al + (size_t)i * KP, lA);
    pack_store(Bh + (size_t)i * KP, hB);
    pack_store(Bl + (size_t)i * KP, lB);
}

// Stage one 128-col B tile (hi+lo, 16KB) transposed to [side][kslot][col*16]:
// linear LDS dest (global_load_lds rule), permuted per-lane global source.
__device__ inline void stage_tile(const unsigned short* __restrict__ Bh,
                                  const unsigned short* __restrict__ Bl,
                                  int imB, int colBase, char* buf, int w, int l) {
#pragma unroll
    for (int j = 0; j < 4; ++j) {
        int q = w * 4 + j;                 // 16 chunks of 1KB
        int side = q >> 3, slot = (q >> 1) & 3, ch = q & 1;
        const unsigned short* src = (side ? Bl : Bh)
            + ((size_t)(imB * NPAD + colBase + ch * 64 + l)) * KP + slot * 8;
        char* dst = buf + side * 8192 + slot * 2048 + ch * 1024;
        __builtin_amdgcn_global_load_lds(
            (const __attribute__((address_space(1))) void*)src,
            (__attribute__((address_space(3))) void*)dst, 16, 0, 0);
    }
}

__device__ inline void item_of(int sym, int xyStrip, int pb, int len1, int idx,
                               int& strip, int& col, float& wt) {
    if (!sym)            { strip = xyStrip;  col = idx;                  wt = 1.0f; }
    else if (idx < len1) { strip = pb;       col = pb + idx;             wt = (idx == 0) ? 1.0f : 2.0f; }
    else                 { strip = 30 - pb;  col = strip + (idx - len1); wt = (idx == len1) ? 1.0f : 2.0f; }
}

// 1984 blocks x <=8 column tiles. 992 xy (b,strip,quarter) + 992 sym
// (type,b,paired-strip,quarter). Two-barrier counted-vmcnt pipeline.
__global__ __launch_bounds__(256) void gp_pairs4(const unsigned short* __restrict__ Ah,
                                                 const unsigned short* __restrict__ Al,
                                                 const unsigned short* __restrict__ Bh,
                                                 const unsigned short* __restrict__ Bl,
                                                 float* __restrict__ acc) {
    __shared__ __align__(16) char lds[2][16384];   // exactly 32KB -> 5 blocks/CU

    const int gid = blockIdx.x;
    int type, b, imA, imB, sym = 0, xyStrip = 0, pb = 0, len1 = 0, i0, i1;
    if (gid < 992) {
        type = 0; b = gid / 124; int r = gid % 124;
        xyStrip = r >> 2; int q = r & 3;
        i0 = q * 8; i1 = (q == 3) ? 31 : i0 + 8;
        imA = b; imB = 8 + b;
    } else {
        sym = 1;
        int id2 = gid - 992; type = 1 + id2 / 496; int r = id2 % 496;
        b = r / 62; int u = r % 62;
        int q;
        if (u >= 60) { pb = 15; q = u - 60; } else { pb = u >> 2; q = u & 3; }
        len1 = 31 - pb;
        i0 = q * 8; i1 = i0 + 8;                 // pb==15: q in {0,1}, total 16
        imA = (type == 1) ? b : 8 + b; imB = imA;
    }

    const int t = threadIdx.x;
    const int w = t >> 6, l = t & 63, l15 = l & 15, lhi = l >> 4;
    const int colw = (w & 1) * 64;

    bf16x8 ah[4], al[4];
    int curStrip = -1;
    float sacc = 0.0f;

    int strip, col; float wt;
    item_of(sym, xyStrip, pb, len1, i0, strip, col, wt);
    stage_tile(Bh, Bl, imB, col * 128, &lds[0][0], w, l);   // i0 is even

    for (int idx = i0; idx < i1; ++idx) {
        const int cur = idx & 1;
        item_of(sym, xyStrip, pb, len1, idx, strip, col, wt);

        // A-frag loads FIRST (older than the prefetch below -> compiler's
        // pre-MFMA wait is vmcnt(4), leaving the prefetch in flight).
        if (strip != curStrip) {
            curStrip = strip;
            int rowBase = strip * 128 + (w >> 1) * 64;
#pragma unroll
            for (int rg = 0; rg < 4; ++rg) {
                size_t e = ((size_t)(imA * NPAD + rowBase + rg * 16 + l15)) * KP + lhi * 8;
                ah[rg] = *(const bf16x8*)(Ah + e);
                al[rg] = *(const bf16x8*)(Al + e);
            }
        }

        if (idx + 1 < i1) {
            int s2, c2; float w2;
            item_of(sym, xyStrip, pb, len1, idx + 1, s2, c2, w2);
            stage_tile(Bh, Bl, imB, c2 * 128, &lds[cur ^ 1][0], w, l);
            // wait current tile's 4 staging loads (oldest), keep prefetch live
            asm volatile("s_waitcnt vmcnt(4)\n\ts_barrier" ::: "memory");
        } else {
            asm volatile("s_waitcnt vmcnt(0)\n\ts_barrier" ::: "memory");
        }

        const char* bb = &lds[cur][0];
        bf16x8 bh[4], bl[4];
#pragma unroll
        for (int cg = 0; cg < 4; ++cg) {
            int off = lhi * 2048 + (colw + cg * 16 + l15) * 16;
            bh[cg] = *(const bf16x8*)(bb + off);
            bl[cg] = *(const bf16x8*)(bb + 8192 + off);
        }

        float s0 = 0.f, s1 = 0.f, s2e = 0.f, s3 = 0.f;
#pragma unroll
        for (int rg = 0; rg < 4; ++rg)
#pragma unroll
            for (int cg = 0; cg < 4; ++cg) {
                f32x4 g = {0.f, 0.f, 0.f, 0.f};
                g = __builtin_amdgcn_mfma_f32_16x16x32_bf16(al[rg], bh[cg], g, 0, 0, 0);
                g = __builtin_amdgcn_mfma_f32_16x16x32_bf16(ah[rg], bl[cg], g, 0, 0, 0);
                g = __builtin_amdgcn_mfma_f32_16x16x32_bf16(ah[rg], bh[cg], g, 0, 0, 0);
                s0  += __builtin_amdgcn_exp2f(g[0]);
                s1  += __builtin_amdgcn_exp2f(g[1]);
                s2e += __builtin_amdgcn_exp2f(g[2]);
                s3  += __builtin_amdgcn_exp2f(g[3]);
            }
        sacc = fmaf(wt, (s0 + s1) + (s2e + s3), sacc);

        // read-protection barrier: own LDS reads landed, no vmcnt drain
        asm volatile("s_waitcnt lgkmcnt(0)\n\ts_barrier" ::: "memory");
    }

    // block reduce (reuse lds; all staging/readers done past last barrier)
#pragma unroll
    for (int o = 32; o > 0; o >>= 1) sacc += __shfl_down(sacc, o, 64);
    float* red = (float*)&lds[0][0];
    if (l == 0) red[w] = sacc;
    __syncthreads();
    if (t == 0) atomicAdd(&acc[type * 8 + b], (red[0] + red[1]) + (red[2] + red[3]));
}

__global__ void gp_final(const float* __restrict__ acc, float* __restrict__ out) {
    if (threadIdx.x == 0) {
        double s = 0.0;
        for (int b = 0; b < 8; ++b)
            s += -2.0 * (double)acc[b] + (double)acc[8 + b] + (double)acc[16 + b];
        out[0] = (float)(s / (8.0 * (double)NP * (double)NP));
    }
}

extern "C" void kernel_launch(void* const* d_in, const int* in_sizes, int n_in,
                              void* d_out, int out_size, void* d_ws, size_t ws_size,
                              hipStream_t stream) {
    const float* x = (const float*)d_in[0];
    const float* y = (const float*)d_in[1];
    const size_t MSZ = (size_t)16 * NPAD * KP;
    unsigned short* Ah = (unsigned short*)d_ws;
    unsigned short* Al = Ah + MSZ;
    unsigned short* Bh = Al + MSZ;
    unsigned short* Bl = Bh + MSZ;
    float* acc = (float*)(Bl + MSZ);

    gp_prep<<<(16 * NPAD) / 256, 256, 0, stream>>>(x, y, Ah, Al, Bh, Bl, acc);
    gp_pairs4<<<1984, 256, 0, stream>>>(Ah, Al, Bh, Bl, acc);
    gp_final<<<1, 1, 0, stream>>>(acc, (float*)d_out);
}